// Round 5
// baseline (395.770 us; speedup 1.0000x reference)
//
#include <hip/hip_runtime.h>
#include <hip/hip_bf16.h>

#define SEQ 2048
#define DM 2048
#define NH 16
#define NKV 4
#define HD 128

typedef float f32x4 __attribute__((ext_vector_type(4)));
typedef short s16x8 __attribute__((ext_vector_type(8)));
typedef short s16x4 __attribute__((ext_vector_type(4)));

__device__ inline __hip_bfloat16 f2b(float f) { return __float2bfloat16(f); }
__device__ inline float b2f_us(unsigned short u) { return __uint_as_float(((unsigned)u) << 16); }
__device__ inline short f2b_s(float f) {
    __hip_bfloat16 h = __float2bfloat16(f);
    return *(short*)&h;
}

// async global->LDS, 16B per lane; HW dest = wave-uniform base + lane*16.
__device__ inline void gl_lds16(const void* g, void* l) {
    __builtin_amdgcn_global_load_lds((const __attribute__((address_space(1))) void*)g,
                                     (__attribute__((address_space(3))) void*)l, 16, 0, 0);
}

// ---------------- cast fp32 -> bf16 ----------------
__global__ void cast_kernel(const float* __restrict__ in, __hip_bfloat16* __restrict__ out, int n) {
    int i = (blockIdx.x * 256 + threadIdx.x) * 4;
    if (i < n) {
        float4 v = *(const float4*)(in + i);
        __hip_bfloat16 o4[4] = {f2b(v.x), f2b(v.y), f2b(v.z), f2b(v.w)};
        *(ushort4*)(out + i) = *(ushort4*)o4;
    }
}

// ---------------- transpose + cast: in[K][N] fp32 -> out[N][K] bf16 ----------------
__global__ void transpose_cast(const float* __restrict__ in, __hip_bfloat16* __restrict__ out,
                               int K, int N) {
    __shared__ float tile[32][33];
    int n0 = blockIdx.x * 32, k0 = blockIdx.y * 32;
    int tx = threadIdx.x, ty = threadIdx.y; // block (32,8)
    for (int r = ty; r < 32; r += 8)
        tile[r][tx] = in[(size_t)(k0 + r) * N + n0 + tx];
    __syncthreads();
    for (int r = ty; r < 32; r += 8)
        out[(size_t)(n0 + r) * K + k0 + tx] = f2b(tile[tx][r]);
}

// ---------------- GEMM: C[M][N] = A[M][Kd] * Bt[N][Kd]^T ----------------
// m97 structure + GROUP_M=8 grouped supertile swizzle.
template <int OUT_F32>
__global__ __launch_bounds__(256, 3) void gemm_bt(
    const __hip_bfloat16* __restrict__ A,
    const __hip_bfloat16* __restrict__ Bt,
    void* __restrict__ Cp, int M, int N, int Kd) {
    __shared__ __hip_bfloat16 As[128 * 64]; // [row][64], swizzled 16B slots
    __shared__ __hip_bfloat16 Bs[128 * 64];
    const int nx = gridDim.x, ny = gridDim.y;
    const int pid = blockIdx.y * nx + blockIdx.x;
    const int GM = 8;
    const int grp = pid / (GM * nx);
    const int first = grp * GM;
    const int gsz = (ny - first < GM) ? (ny - first) : GM;
    const int mt = first + (pid % gsz);
    const int ntile = (pid % (GM * nx)) / gsz;
    const int m0 = mt * 128, n0 = ntile * 128;

    const int t = threadIdx.x;
    const int wv = t >> 6, lane = t & 63;
    const int wm = (wv >> 1) * 64, wn = (wv & 1) * 64;
    const int lrow = lane & 15, quad = lane >> 4;
    f32x4 acc[4][4];
    f32x4 z4 = {0.f, 0.f, 0.f, 0.f};
    for (int i = 0; i < 4; ++i)
        for (int j = 0; j < 4; ++j) acc[i][j] = z4;

    for (int k0 = 0; k0 < Kd; k0 += 64) {
        __syncthreads();
        for (int i = 0; i < 4; ++i) {
            int flat = i * 256 + t;          // 16B slot id
            int row = flat >> 3;
            int cb = (flat & 7) ^ (row & 7); // logical 16B-block for this slot
            gl_lds16(A + (size_t)(m0 + row) * Kd + k0 + cb * 8, &As[flat * 8]);
            gl_lds16(Bt + (size_t)(n0 + row) * Kd + k0 + cb * 8, &Bs[flat * 8]);
        }
        __syncthreads();
        for (int kk = 0; kk < 2; ++kk) {
            s16x8 af[4], bf[4];
            for (int i = 0; i < 4; ++i) {
                int ra = wm + i * 16 + lrow;
                int rb = wn + i * 16 + lrow;
                int pba = ((kk * 4 + quad) ^ (ra & 7)) * 8;
                int pbb = ((kk * 4 + quad) ^ (rb & 7)) * 8;
                af[i] = *(const s16x8*)&As[ra * 64 + pba];
                bf[i] = *(const s16x8*)&Bs[rb * 64 + pbb];
            }
            for (int i = 0; i < 4; ++i)
                for (int j = 0; j < 4; ++j)
                    acc[i][j] = __builtin_amdgcn_mfma_f32_16x16x32_bf16(af[i], bf[j],
                                                                        acc[i][j], 0, 0, 0);
        }
    }
    for (int i = 0; i < 4; ++i)
        for (int j = 0; j < 4; ++j)
            for (int r = 0; r < 4; ++r) {
                int m = m0 + wm + i * 16 + quad * 4 + r;
                int n = n0 + wn + j * 16 + lrow;
                if (OUT_F32)
                    ((float*)Cp)[(size_t)m * N + n] = acc[i][j][r];
                else
                    ((__hip_bfloat16*)Cp)[(size_t)m * N + n] = f2b(acc[i][j][r]);
            }
}

// ---------------- RoPE + reshape (q, k only), vectorized ----------------
// Q is pre-scaled by softmax_scale * log2(e) so attention runs in the exp2 domain
// with no per-score multiply. K is unscaled. (Verified R9/R10/R11: absmax unchanged.)
#define QSC 0.12751744f /* (1/sqrt(128)) * 1.4426950408889634 */
__global__ void rope_reshape(const __hip_bfloat16* __restrict__ qkv,
                             const float* __restrict__ fcos, const float* __restrict__ fsin,
                             __hip_bfloat16* __restrict__ q, __hip_bfloat16* __restrict__ k) {
    int tok = blockIdx.x; // b*SEQ + s
    int b = tok >> 11, s = tok & 2047;
    const __hip_bfloat16* row = qkv + (size_t)tok * 3072;
    for (int it = threadIdx.x; it < 320; it += 256) { // 2560 elems / 8
        int col = it * 8;
        s16x8 v = *(const s16x8*)(row + col);
        int p0 = (col & 127) >> 1;
        f32x4 c4 = *(const f32x4*)(fcos + s * 64 + p0);
        f32x4 s4 = *(const f32x4*)(fsin + s * 64 + p0);
        float scl = (col < 2048) ? QSC : 1.0f;
        short outv[8];
        for (int p = 0; p < 4; ++p) {
            float x0 = b2f_us((unsigned short)v[2 * p]);
            float x1 = b2f_us((unsigned short)v[2 * p + 1]);
            outv[2 * p] = f2b_s((x0 * c4[p] - x1 * s4[p]) * scl);
            outv[2 * p + 1] = f2b_s((x0 * s4[p] + x1 * c4[p]) * scl);
        }
        int d = col & 127;
        if (col < 2048) {
            int h = col >> 7;
            *(s16x8*)(q + ((size_t)((b * NH + h) * SEQ + s)) * HD + d) = *(s16x8*)outv;
        } else {
            int h = (col - 2048) >> 7;
            *(s16x8*)(k + ((size_t)((b * NKV + h) * SEQ + s)) * HD + d) = *(s16x8*)outv;
        }
    }
}

// ---------------- V transpose via LDS: qkv v-cols -> vt[b][kv][d][s] ----------------
__global__ void vtrans(const __hip_bfloat16* __restrict__ qkv, __hip_bfloat16* __restrict__ vt) {
    __shared__ __hip_bfloat16 tile[128][136];
    int s0 = blockIdx.x * 128;
    int bh = blockIdx.y; // b*NKV + kvh
    int b = bh >> 2, kvh = bh & 3;
    int t = threadIdx.x;
    for (int i = 0; i < 8; ++i) {
        int flat = (i * 256 + t) * 8;
        int row = flat >> 7, col = flat & 127;
        *(s16x8*)&tile[row][col] =
            *(const s16x8*)(qkv + (size_t)(b * SEQ + s0 + row) * 3072 + 2560 + kvh * 128 + col);
    }
    __syncthreads();
    for (int i = 0; i < 8; ++i) {
        int dd = i * 16 + (t >> 4);
        int ss = (t & 15) * 8;
        __hip_bfloat16 tmp[8];
        for (int j = 0; j < 8; ++j) tmp[j] = tile[ss + j][dd];
        *(s16x8*)(vt + ((size_t)((b * NKV + kvh) * HD + dd)) * SEQ + s0 + ss) = *(s16x8*)tmp;
    }
}

// ---------------- causal flash attention (GQA), 128 q-rows / 512 threads ----------------
// R12: budget model from R8/R11 counters showed the LDS pipe is the critical resource
// (~60us of the 81us dispatch: 32 b128 reads/wave-tile at ~12cyc + 14us conflicts),
// which is why VALU cuts, barrier halving and setprio were all neutral.
// Change: K is REMOVED from LDS. QK A-fragments load directly from global (L2-resident,
// 512KB per (b,kvh)): per lane addr = row*256B + ks*64B + quad*16B, depth-2 pipelined
// over nt (kf[2][4], fully unrolled -> static indexing, no scratch). First batch issues
// BEFORE the barrier so L2 latency hides under barrier wait. LDS keeps only dbuf V
// (36,864B). Kept: exp2-domain softmax (pre-scaled Q), defer-max, V posOf permute,
// anti-correlated q-tile mapping, one barrier per tile.
__global__ __launch_bounds__(512, 4) void attn_kernel(
    const __hip_bfloat16* __restrict__ q, const __hip_bfloat16* __restrict__ k,
    const __hip_bfloat16* __restrict__ vt, __hip_bfloat16* __restrict__ o) {
    __shared__ __hip_bfloat16 Vs[2][128][72]; // d x keys (key columns permuted by posOf)

    const int bh = blockIdx.y;
    const int bx = (bh < 16) ? (int)(gridDim.x - 1 - blockIdx.x) : (int)blockIdx.x;
    const int b = bh >> 4, h = bh & 15;
    const int kvh = h >> 2;
    const int t = threadIdx.x;
    const int w = t >> 6, lane = t & 63;
    const int lrow = lane & 15, quad = lane >> 4;
    const int q0 = bx * 128;
    const int qrow = q0 + w * 16 + lrow; // this lane's ONE q row (n-dim)

    // Q fragments, B-operand role: n=qrow (lrow), k=d (quad*8+j). Pre-scaled in rope.
    const __hip_bfloat16* qp = q + ((size_t)((b * NH + h) * SEQ + qrow)) * HD;
    s16x8 qf[4];
    for (int ks = 0; ks < 4; ++ks) qf[ks] = *(const s16x8*)(qp + ks * 32 + quad * 8);

    float m_i = -1e30f, l_i = 0.f;
    f32x4 accO[8];
    f32x4 z4 = {0.f, 0.f, 0.f, 0.f};
    for (int d = 0; d < 8; ++d) accO[d] = z4;

    const __hip_bfloat16* kbase = k + ((size_t)(b * NKV + kvh) * SEQ) * HD;
    const __hip_bfloat16* vbase = vt + ((size_t)(b * NKV + kvh) * HD) * SEQ;

    // Per-lane K-fragment base: A-operand of mfma(K,Q) -> row=lrow, d-col=quad*8(+j).
    // Fragment (kt,nt,ks) lives at kfrag + (kt*64 + nt*16)*HD + ks*32.
    const __hip_bfloat16* kfrag = kbase + (size_t)lrow * HD + quad * 8;

    s16x8 vr[2];
    auto load_v = [&](int kt) {
        for (int i = 0; i < 2; ++i) {
            int flat = (i * 512 + t) * 8;
            vr[i] = *(const s16x8*)(vbase + (size_t)(flat >> 6) * SEQ + kt * 64 + (flat & 63));
        }
    };
    auto store_v = [&](int bsel) {
        for (int i = 0; i < 2; ++i) {
            int flat = (i * 512 + t) * 8;
            // V: permuted key columns. Lane holds keys k0..k0+7 (k0 = 8-aligned);
            // they land at posOf base..base+3 and base+8..base+11.
            int row = flat >> 6, k0 = flat & 63;
            int pb = ((k0 >> 5) << 5) | (((k0 >> 2) & 2) << 3) | (((k0 >> 4) & 1) << 2);
            s16x4 lo = {vr[i][0], vr[i][1], vr[i][2], vr[i][3]};
            s16x4 hi = {vr[i][4], vr[i][5], vr[i][6], vr[i][7]};
            *(s16x4*)&Vs[bsel][row][pb] = lo;
            *(s16x4*)&Vs[bsel][row][pb + 8] = hi;
        }
    };

    const int nkt = 2 * bx + 2; // keys [0, q0+128)
    load_v(0);
    store_v(0);

    for (int kt = 0; kt < nkt; ++kt) {
        const int cur = kt & 1;
        const bool more = (kt + 1) < nkt;
        const bool wave_active = (kt * 64 <= q0 + w * 16 + 15);
        const bool mtile = (kt >= 2 * bx); // tile may touch the diagonal
        const __hip_bfloat16* ktb = kfrag + (size_t)kt * 64 * HD;

        s16x8 kf[2][4];
        if (wave_active) { // issue nt=0 K loads BEFORE the barrier (L2 latency hides)
#pragma unroll
            for (int ks = 0; ks < 4; ++ks) kf[0][ks] = *(const s16x8*)(ktb + ks * 32);
        }
        __syncthreads(); // Vs[cur] ready (stored last iter / prologue)
        if (more) load_v(kt + 1); // global->reg, hidden under compute

        if (wave_active) {
            float sv[4][4];
#pragma unroll
            for (int nt = 0; nt < 4; ++nt) {
                if (nt < 3) { // prefetch next nt's K fragments (depth-2 pipeline)
#pragma unroll
                    for (int ks = 0; ks < 4; ++ks)
                        kf[(nt + 1) & 1][ks] =
                            *(const s16x8*)(ktb + (nt + 1) * 16 * HD + ks * 32);
                }
                f32x4 sacc = z4;
#pragma unroll
                for (int ks = 0; ks < 4; ++ks)
                    sacc = __builtin_amdgcn_mfma_f32_16x16x32_bf16(kf[nt & 1][ks], qf[ks],
                                                                   sacc, 0, 0, 0);
                if (mtile) {
                    for (int r = 0; r < 4; ++r) {
                        int key = kt * 64 + nt * 16 + quad * 4 + r;
                        sv[nt][r] = (key > qrow) ? -1e30f : sacc[r];
                    }
                } else {
                    for (int r = 0; r < 4; ++r) sv[nt][r] = sacc[r];
                }
            }
            float mt2 = fmaxf(fmaxf(fmaxf(sv[0][0], sv[0][1]), fmaxf(sv[0][2], sv[0][3])),
                              fmaxf(fmaxf(sv[1][0], sv[1][1]), fmaxf(sv[1][2], sv[1][3])));
            mt2 = fmaxf(mt2,
                        fmaxf(fmaxf(fmaxf(sv[2][0], sv[2][1]), fmaxf(sv[2][2], sv[2][3])),
                              fmaxf(fmaxf(sv[3][0], sv[3][1]), fmaxf(sv[3][2], sv[3][3]))));
            mt2 = fmaxf(mt2, __shfl_xor(mt2, 16, 64));
            mt2 = fmaxf(mt2, __shfl_xor(mt2, 32, 64));
            // defer-max: only rescale when the running max grew by >8 (exp2 domain,
            // deferred p bounded by 2^8 -- safe in f32/bf16).
            if (!__all(mt2 <= m_i + 8.f)) {
                float mn = fmaxf(m_i, mt2);
                float alpha = exp2f(m_i - mn);
                l_i *= alpha;
                for (int d = 0; d < 8; ++d)
                    for (int r = 0; r < 4; ++r) accO[d][r] *= alpha;
                m_i = mn;
            }
            // P built fully in-register; k-slot (quad,j) of PV mfma#0 is permuted
            // position quad*8+j  <->  key (j>>2)*16 + quad*4 + (j&3) = sv[j>>2][j&3].
            float rs = 0.f;
            s16x8 pf0, pf1;
#pragma unroll
            for (int j = 0; j < 8; ++j) {
                float p0 = exp2f(sv[j >> 2][j & 3] - m_i);
                float p1 = exp2f(sv[2 + (j >> 2)][j & 3] - m_i);
                rs += p0 + p1;
                pf0[j] = f2b_s(p0);
                pf1[j] = f2b_s(p1);
            }
            rs += __shfl_xor(rs, 16, 64);
            rs += __shfl_xor(rs, 32, 64);
            l_i += rs;
            for (int dt = 0; dt < 8; ++dt) {
                s16x8 vf0 = *(const s16x8*)&Vs[cur][dt * 16 + lrow][quad * 8];
                s16x8 vf1 = *(const s16x8*)&Vs[cur][dt * 16 + lrow][32 + quad * 8];
                accO[dt] = __builtin_amdgcn_mfma_f32_16x16x32_bf16(vf0, pf0, accO[dt], 0, 0, 0);
                accO[dt] = __builtin_amdgcn_mfma_f32_16x16x32_bf16(vf1, pf1, accO[dt], 0, 0, 0);
            }
        }

        if (more) store_v(1 - cur); // write buffer nobody reads this iter
    }
    float inv = 1.0f / l_i;
    __hip_bfloat16* op = o + (size_t)(b * SEQ + qrow) * DM + h * HD;
    for (int dt = 0; dt < 8; ++dt) {
        short ov[4];
        for (int r = 0; r < 4; ++r) ov[r] = f2b_s(accO[dt][r] * inv);
        *(s16x4*)(op + dt * 16 + quad * 4) = *(s16x4*)ov;
    }
}

extern "C" void kernel_launch(void* const* d_in, const int* in_sizes, int n_in,
                              void* d_out, int out_size, void* d_ws, size_t ws_size,
                              hipStream_t stream) {
    (void)in_sizes; (void)n_in; (void)out_size; (void)ws_size;
    const float* x  = (const float*)d_in[0];
    const float* fc = (const float*)d_in[1];
    const float* fs = (const float*)d_in[2];
    // d_in[3] = mask: exactly causal, applied analytically
    const float* wq = (const float*)d_in[4];
    const float* wk = (const float*)d_in[5];
    const float* wv = (const float*)d_in[6];
    const float* wo = (const float*)d_in[7];

    __hip_bfloat16* xb    = (__hip_bfloat16*)d_ws;            // [4096][2048]
    __hip_bfloat16* wqkvt = xb + (size_t)8388608;             // [3072][2048]
    __hip_bfloat16* wot   = wqkvt + (size_t)6291456;          // [2048][2048]
    __hip_bfloat16* qkv   = wot + (size_t)4194304;            // [4096][3072]
    __hip_bfloat16* qb    = xb;                               // aliases xb
    __hip_bfloat16* kb    = wqkvt;                            // aliases wqkvt
    __hip_bfloat16* vtb   = wqkvt + (size_t)2097152;
    __hip_bfloat16* attno = qkv;                              // aliases qkv

    cast_kernel<<<8192, 256, 0, stream>>>(x, xb, 8388608);
    transpose_cast<<<dim3(64, 64), dim3(32, 8), 0, stream>>>(wq, wqkvt, 2048, 2048);
    transpose_cast<<<dim3(16, 64), dim3(32, 8), 0, stream>>>(wk, wqkvt + (size_t)2048 * 2048, 2048, 512);
    transpose_cast<<<dim3(16, 64), dim3(32, 8), 0, stream>>>(wv, wqkvt + (size_t)2560 * 2048, 2048, 512);
    transpose_cast<<<dim3(64, 64), dim3(32, 8), 0, stream>>>(wo, wot, 2048, 2048);
    gemm_bt<0><<<dim3(24, 32), 256, 0, stream>>>(xb, wqkvt, qkv, 4096, 3072, 2048);
    rope_reshape<<<4096, 256, 0, stream>>>(qkv, fc, fs, qb, kb);
    vtrans<<<dim3(16, 8), 256, 0, stream>>>(qkv, vtb);
    attn_kernel<<<dim3(16, 32), 512, 0, stream>>>(qb, kb, vtb, attno);
    gemm_bt<1><<<dim3(16, 32), 256, 0, stream>>>(attno, wot, d_out, 4096, 2048, 2048);
}

// Round 6
// 325.749 us; speedup vs baseline: 1.2150x; 1.2150x over previous
//
#include <hip/hip_runtime.h>
#include <hip/hip_bf16.h>

#define SEQ 2048
#define DM 2048
#define NH 16
#define NKV 4
#define HD 128

typedef float f32x4 __attribute__((ext_vector_type(4)));
typedef short s16x8 __attribute__((ext_vector_type(8)));
typedef short s16x4 __attribute__((ext_vector_type(4)));

__device__ inline __hip_bfloat16 f2b(float f) { return __float2bfloat16(f); }
__device__ inline float b2f_us(unsigned short u) { return __uint_as_float(((unsigned)u) << 16); }
__device__ inline short f2b_s(float f) {
    __hip_bfloat16 h = __float2bfloat16(f);
    return *(short*)&h;
}

// async global->LDS, 16B per lane; HW dest = wave-uniform base + lane*16.
__device__ inline void gl_lds16(const void* g, void* l) {
    __builtin_amdgcn_global_load_lds((const __attribute__((address_space(1))) void*)g,
                                     (__attribute__((address_space(3))) void*)l, 16, 0, 0);
}

// ---------------- fused prep: cast x->bf16  +  4x transpose_cast (weights) ----------
// R13: 5 launches -> 1. Block ranges (256 threads each):
//   [0, 8192)        cast x (8,388,608 f32, 4/thread)
//   [8192, 12288)    wq^T  -> wqkvt rows 0..2047      (64x64 tiles of 32)
//   [12288, 13312)   wk^T  -> wqkvt rows 2048..2559   (16x64)
//   [13312, 14336)   wv^T  -> wqkvt rows 2560..3071   (16x64)
//   [14336, 18432)   wo^T  -> wot                     (64x64)
__global__ void prep_kernel(const float* __restrict__ x,
                            const float* __restrict__ wq, const float* __restrict__ wk,
                            const float* __restrict__ wv, const float* __restrict__ wo,
                            __hip_bfloat16* __restrict__ xb,
                            __hip_bfloat16* __restrict__ wqkvt,
                            __hip_bfloat16* __restrict__ wot) {
    __shared__ float tile[32][33];
    int bid = blockIdx.x;
    const int t = threadIdx.x;
    if (bid < 8192) {
        int i = (bid * 256 + t) * 4;
        float4 v = *(const float4*)(x + i);
        __hip_bfloat16 o4[4] = {f2b(v.x), f2b(v.y), f2b(v.z), f2b(v.w)};
        *(ushort4*)(xb + i) = *(ushort4*)o4;
        return;
    }
    bid -= 8192;
    const float* in;
    __hip_bfloat16* out;
    int N, bx, by;
    if (bid < 4096) {
        in = wq; out = wqkvt; N = 2048; bx = bid & 63; by = bid >> 6;
    } else if (bid < 5120) {
        bid -= 4096; in = wk; out = wqkvt + (size_t)2048 * 2048; N = 512; bx = bid & 15; by = bid >> 4;
    } else if (bid < 6144) {
        bid -= 5120; in = wv; out = wqkvt + (size_t)2560 * 2048; N = 512; bx = bid & 15; by = bid >> 4;
    } else {
        bid -= 6144; in = wo; out = wot; N = 2048; bx = bid & 63; by = bid >> 6;
    }
    const int K = 2048;
    int n0 = bx * 32, k0 = by * 32;
    int tx = t & 31, ty = t >> 5; // logical (32,8)
    for (int r = ty; r < 32; r += 8)
        tile[r][tx] = in[(size_t)(k0 + r) * N + n0 + tx];
    __syncthreads();
    for (int r = ty; r < 32; r += 8)
        out[(size_t)(n0 + r) * K + k0 + tx] = f2b(tile[tx][r]);
}

// ---------------- GEMM: C[M][N] = A[M][Kd] * Bt[N][Kd]^T ----------------
// m97 structure + GROUP_M=8 grouped supertile swizzle.
template <int OUT_F32>
__global__ __launch_bounds__(256, 3) void gemm_bt(
    const __hip_bfloat16* __restrict__ A,
    const __hip_bfloat16* __restrict__ Bt,
    void* __restrict__ Cp, int M, int N, int Kd) {
    __shared__ __hip_bfloat16 As[128 * 64]; // [row][64], swizzled 16B slots
    __shared__ __hip_bfloat16 Bs[128 * 64];
    const int nx = gridDim.x, ny = gridDim.y;
    const int pid = blockIdx.y * nx + blockIdx.x;
    const int GM = 8;
    const int grp = pid / (GM * nx);
    const int first = grp * GM;
    const int gsz = (ny - first < GM) ? (ny - first) : GM;
    const int mt = first + (pid % gsz);
    const int ntile = (pid % (GM * nx)) / gsz;
    const int m0 = mt * 128, n0 = ntile * 128;

    const int t = threadIdx.x;
    const int wv = t >> 6, lane = t & 63;
    const int wm = (wv >> 1) * 64, wn = (wv & 1) * 64;
    const int lrow = lane & 15, quad = lane >> 4;
    f32x4 acc[4][4];
    f32x4 z4 = {0.f, 0.f, 0.f, 0.f};
    for (int i = 0; i < 4; ++i)
        for (int j = 0; j < 4; ++j) acc[i][j] = z4;

    for (int k0 = 0; k0 < Kd; k0 += 64) {
        __syncthreads();
        for (int i = 0; i < 4; ++i) {
            int flat = i * 256 + t;          // 16B slot id
            int row = flat >> 3;
            int cb = (flat & 7) ^ (row & 7); // logical 16B-block for this slot
            gl_lds16(A + (size_t)(m0 + row) * Kd + k0 + cb * 8, &As[flat * 8]);
            gl_lds16(Bt + (size_t)(n0 + row) * Kd + k0 + cb * 8, &Bs[flat * 8]);
        }
        __syncthreads();
        for (int kk = 0; kk < 2; ++kk) {
            s16x8 af[4], bf[4];
            for (int i = 0; i < 4; ++i) {
                int ra = wm + i * 16 + lrow;
                int rb = wn + i * 16 + lrow;
                int pba = ((kk * 4 + quad) ^ (ra & 7)) * 8;
                int pbb = ((kk * 4 + quad) ^ (rb & 7)) * 8;
                af[i] = *(const s16x8*)&As[ra * 64 + pba];
                bf[i] = *(const s16x8*)&Bs[rb * 64 + pbb];
            }
            for (int i = 0; i < 4; ++i)
                for (int j = 0; j < 4; ++j)
                    acc[i][j] = __builtin_amdgcn_mfma_f32_16x16x32_bf16(af[i], bf[j],
                                                                        acc[i][j], 0, 0, 0);
        }
    }
    for (int i = 0; i < 4; ++i)
        for (int j = 0; j < 4; ++j)
            for (int r = 0; r < 4; ++r) {
                int m = m0 + wm + i * 16 + quad * 4 + r;
                int n = n0 + wn + j * 16 + lrow;
                if (OUT_F32)
                    ((float*)Cp)[(size_t)m * N + n] = acc[i][j][r];
                else
                    ((__hip_bfloat16*)Cp)[(size_t)m * N + n] = f2b(acc[i][j][r]);
            }
}

// ---------------- fused RoPE(q,k) + V-transpose ----------------
// Q is pre-scaled by softmax_scale * log2(e) so attention runs in the exp2 domain
// with no per-score multiply. K is unscaled. (Verified R9-R11: absmax unchanged.)
// Block ranges: [0,4096) rope token blocks; [4096,4224) vtrans tiles (16 x 8).
#define QSC 0.12751744f /* (1/sqrt(128)) * 1.4426950408889634 */
__global__ void rv_kernel(const __hip_bfloat16* __restrict__ qkv,
                          const float* __restrict__ fcos, const float* __restrict__ fsin,
                          __hip_bfloat16* __restrict__ q, __hip_bfloat16* __restrict__ k,
                          __hip_bfloat16* __restrict__ vt) {
    __shared__ __hip_bfloat16 tile[128][136];
    const int t = threadIdx.x;
    if (blockIdx.x < 4096) {
        int tok = blockIdx.x; // b*SEQ + s
        int b = tok >> 11, s = tok & 2047;
        const __hip_bfloat16* row = qkv + (size_t)tok * 3072;
        for (int it = t; it < 320; it += 256) { // 2560 elems / 8
            int col = it * 8;
            s16x8 v = *(const s16x8*)(row + col);
            int p0 = (col & 127) >> 1;
            f32x4 c4 = *(const f32x4*)(fcos + s * 64 + p0);
            f32x4 s4 = *(const f32x4*)(fsin + s * 64 + p0);
            float scl = (col < 2048) ? QSC : 1.0f;
            short outv[8];
            for (int p = 0; p < 4; ++p) {
                float x0 = b2f_us((unsigned short)v[2 * p]);
                float x1 = b2f_us((unsigned short)v[2 * p + 1]);
                outv[2 * p] = f2b_s((x0 * c4[p] - x1 * s4[p]) * scl);
                outv[2 * p + 1] = f2b_s((x0 * s4[p] + x1 * c4[p]) * scl);
            }
            int d = col & 127;
            if (col < 2048) {
                int h = col >> 7;
                *(s16x8*)(q + ((size_t)((b * NH + h) * SEQ + s)) * HD + d) = *(s16x8*)outv;
            } else {
                int h = (col - 2048) >> 7;
                *(s16x8*)(k + ((size_t)((b * NKV + h) * SEQ + s)) * HD + d) = *(s16x8*)outv;
            }
        }
        return;
    }
    int r = blockIdx.x - 4096;
    int s0 = (r & 15) * 128;
    int bh = r >> 4; // b*NKV + kvh
    int b = bh >> 2, kvh = bh & 3;
    for (int i = 0; i < 8; ++i) {
        int flat = (i * 256 + t) * 8;
        int row = flat >> 7, col = flat & 127;
        *(s16x8*)&tile[row][col] =
            *(const s16x8*)(qkv + (size_t)(b * SEQ + s0 + row) * 3072 + 2560 + kvh * 128 + col);
    }
    __syncthreads();
    for (int i = 0; i < 8; ++i) {
        int dd = i * 16 + (t >> 4);
        int ss = (t & 15) * 8;
        __hip_bfloat16 tmp[8];
        for (int j = 0; j < 8; ++j) tmp[j] = tile[ss + j][dd];
        *(s16x8*)(vt + ((size_t)((b * NKV + kvh) * HD + dd)) * SEQ + s0 + ss) = *(s16x8*)tmp;
    }
}

// ---------------- causal flash attention (GQA), 128 q-rows / 512 threads ----------------
// R13 = exact revert to R11 (measured best: 80.7us). R12's K-direct-from-global
// regressed 81->148us (scattered 256B-stride lanes -> ~16 txn/load on the VMEM pipe);
// LDS b128 staging is strictly better for K. Structure: no Ps round-trip (V posOf
// permute, P feeds PV from regs), K/V double-buffered (one barrier/tile), exp2-domain
// softmax on pre-scaled Q, defer-max (T13), setprio around MFMA clusters,
// anti-correlated q-tile mapping (co-resident pairs sum to 34 steps).
__global__ __launch_bounds__(512, 4) void attn_kernel(
    const __hip_bfloat16* __restrict__ q, const __hip_bfloat16* __restrict__ k,
    const __hip_bfloat16* __restrict__ vt, __hip_bfloat16* __restrict__ o) {
    __shared__ __hip_bfloat16 Ks[2][64][136];  // keys x d, double-buffered
    __shared__ __hip_bfloat16 Vs[2][128][72];  // d x keys (key columns permuted by posOf)

    const int bh = blockIdx.y;
    const int bx = (bh < 16) ? (int)(gridDim.x - 1 - blockIdx.x) : (int)blockIdx.x;
    const int b = bh >> 4, h = bh & 15;
    const int kvh = h >> 2;
    const int t = threadIdx.x;
    const int w = t >> 6, lane = t & 63;
    const int lrow = lane & 15, quad = lane >> 4;
    const int q0 = bx * 128;
    const int qrow = q0 + w * 16 + lrow; // this lane's ONE q row (n-dim)

    // Q fragments, B-operand role: n=qrow (lrow), k=d (quad*8+j). Pre-scaled in rope.
    const __hip_bfloat16* qp = q + ((size_t)((b * NH + h) * SEQ + qrow)) * HD;
    s16x8 qf[4];
    for (int ks = 0; ks < 4; ++ks) qf[ks] = *(const s16x8*)(qp + ks * 32 + quad * 8);

    float m_i = -1e30f, l_i = 0.f;
    f32x4 accO[8];
    f32x4 z4 = {0.f, 0.f, 0.f, 0.f};
    for (int d = 0; d < 8; ++d) accO[d] = z4;

    const __hip_bfloat16* kbase = k + ((size_t)(b * NKV + kvh) * SEQ) * HD;
    const __hip_bfloat16* vbase = vt + ((size_t)(b * NKV + kvh) * HD) * SEQ;

    s16x8 kr[2], vr[2];
    auto load_tile = [&](int kt) {
        for (int i = 0; i < 2; ++i) {
            int flat = (i * 512 + t) * 8;
            kr[i] = *(const s16x8*)(kbase + (size_t)(kt * 64 + (flat >> 7)) * HD + (flat & 127));
            vr[i] = *(const s16x8*)(vbase + (size_t)(flat >> 6) * SEQ + kt * 64 + (flat & 63));
        }
    };
    auto store_tile = [&](int bsel) {
        for (int i = 0; i < 2; ++i) {
            int flat = (i * 512 + t) * 8;
            *(s16x8*)&Ks[bsel][flat >> 7][flat & 127] = kr[i];
            // V: permuted key columns. Lane holds keys k0..k0+7 (k0 = 8-aligned);
            // they land at posOf base..base+3 and base+8..base+11.
            int row = flat >> 6, k0 = flat & 63;
            int pb = ((k0 >> 5) << 5) | (((k0 >> 2) & 2) << 3) | (((k0 >> 4) & 1) << 2);
            s16x4 lo = {vr[i][0], vr[i][1], vr[i][2], vr[i][3]};
            s16x4 hi = {vr[i][4], vr[i][5], vr[i][6], vr[i][7]};
            *(s16x4*)&Vs[bsel][row][pb] = lo;
            *(s16x4*)&Vs[bsel][row][pb + 8] = hi;
        }
    };

    const int nkt = 2 * bx + 2; // keys [0, q0+128)
    load_tile(0);
    store_tile(0);

    for (int kt = 0; kt < nkt; ++kt) {
        const int cur = kt & 1;
        bool more = (kt + 1) < nkt;
        __syncthreads(); // buf[cur] ready (stored last iter / prologue)
        if (more) load_tile(kt + 1); // global->reg, hidden under compute
        bool wave_active = (kt * 64 <= q0 + w * 16 + 15);
        bool mtile = (kt >= 2 * bx); // tile may touch the diagonal

        if (wave_active) {
            float sv[4][4];
            __builtin_amdgcn_s_setprio(1);
            for (int nt = 0; nt < 4; ++nt) {
                f32x4 sacc = z4;
                for (int ks = 0; ks < 4; ++ks) {
                    s16x8 kf = *(const s16x8*)&Ks[cur][nt * 16 + lrow][ks * 32 + quad * 8];
                    sacc = __builtin_amdgcn_mfma_f32_16x16x32_bf16(kf, qf[ks], sacc, 0, 0, 0);
                }
                if (mtile) {
                    for (int r = 0; r < 4; ++r) {
                        int key = kt * 64 + nt * 16 + quad * 4 + r;
                        sv[nt][r] = (key > qrow) ? -1e30f : sacc[r];
                    }
                } else {
                    for (int r = 0; r < 4; ++r) sv[nt][r] = sacc[r];
                }
            }
            __builtin_amdgcn_s_setprio(0);
            float mt2 = fmaxf(fmaxf(fmaxf(sv[0][0], sv[0][1]), fmaxf(sv[0][2], sv[0][3])),
                              fmaxf(fmaxf(sv[1][0], sv[1][1]), fmaxf(sv[1][2], sv[1][3])));
            mt2 = fmaxf(mt2,
                        fmaxf(fmaxf(fmaxf(sv[2][0], sv[2][1]), fmaxf(sv[2][2], sv[2][3])),
                              fmaxf(fmaxf(sv[3][0], sv[3][1]), fmaxf(sv[3][2], sv[3][3]))));
            mt2 = fmaxf(mt2, __shfl_xor(mt2, 16, 64));
            mt2 = fmaxf(mt2, __shfl_xor(mt2, 32, 64));
            // defer-max: only rescale when the running max grew by >8 (exp2 domain,
            // deferred p bounded by 2^8 -- safe in f32/bf16).
            if (!__all(mt2 <= m_i + 8.f)) {
                float mn = fmaxf(m_i, mt2);
                float alpha = exp2f(m_i - mn);
                l_i *= alpha;
                for (int d = 0; d < 8; ++d)
                    for (int r = 0; r < 4; ++r) accO[d][r] *= alpha;
                m_i = mn;
            }
            // P built fully in-register; k-slot (quad,j) of PV mfma#0 is permuted
            // position quad*8+j  <->  key (j>>2)*16 + quad*4 + (j&3) = sv[j>>2][j&3].
            float rs = 0.f;
            s16x8 pf0, pf1;
#pragma unroll
            for (int j = 0; j < 8; ++j) {
                float p0 = exp2f(sv[j >> 2][j & 3] - m_i);
                float p1 = exp2f(sv[2 + (j >> 2)][j & 3] - m_i);
                rs += p0 + p1;
                pf0[j] = f2b_s(p0);
                pf1[j] = f2b_s(p1);
            }
            rs += __shfl_xor(rs, 16, 64);
            rs += __shfl_xor(rs, 32, 64);
            l_i += rs;
            __builtin_amdgcn_s_setprio(1);
            for (int dt = 0; dt < 8; ++dt) {
                s16x8 vf0 = *(const s16x8*)&Vs[cur][dt * 16 + lrow][quad * 8];
                s16x8 vf1 = *(const s16x8*)&Vs[cur][dt * 16 + lrow][32 + quad * 8];
                accO[dt] = __builtin_amdgcn_mfma_f32_16x16x32_bf16(vf0, pf0, accO[dt], 0, 0, 0);
                accO[dt] = __builtin_amdgcn_mfma_f32_16x16x32_bf16(vf1, pf1, accO[dt], 0, 0, 0);
            }
            __builtin_amdgcn_s_setprio(0);
        }

        if (more) store_tile(1 - cur); // write buffer nobody reads this iter
    }
    float inv = 1.0f / l_i;
    __hip_bfloat16* op = o + (size_t)(b * SEQ + qrow) * DM + h * HD;
    for (int dt = 0; dt < 8; ++dt) {
        short ov[4];
        for (int r = 0; r < 4; ++r) ov[r] = f2b_s(accO[dt][r] * inv);
        *(s16x4*)(op + dt * 16 + quad * 4) = *(s16x4*)ov;
    }
}

extern "C" void kernel_launch(void* const* d_in, const int* in_sizes, int n_in,
                              void* d_out, int out_size, void* d_ws, size_t ws_size,
                              hipStream_t stream) {
    (void)in_sizes; (void)n_in; (void)out_size; (void)ws_size;
    const float* x  = (const float*)d_in[0];
    const float* fc = (const float*)d_in[1];
    const float* fs = (const float*)d_in[2];
    // d_in[3] = mask: exactly causal, applied analytically
    const float* wq = (const float*)d_in[4];
    const float* wk = (const float*)d_in[5];
    const float* wv = (const float*)d_in[6];
    const float* wo = (const float*)d_in[7];

    __hip_bfloat16* xb    = (__hip_bfloat16*)d_ws;            // [4096][2048]
    __hip_bfloat16* wqkvt = xb + (size_t)8388608;             // [3072][2048]
    __hip_bfloat16* wot   = wqkvt + (size_t)6291456;          // [2048][2048]
    __hip_bfloat16* qkv   = wot + (size_t)4194304;            // [4096][3072]
    __hip_bfloat16* qb    = xb;                               // aliases xb
    __hip_bfloat16* kb    = wqkvt;                            // aliases wqkvt
    __hip_bfloat16* vtb   = wqkvt + (size_t)2097152;
    __hip_bfloat16* attno = qkv;                              // aliases qkv

    prep_kernel<<<18432, 256, 0, stream>>>(x, wq, wk, wv, wo, xb, wqkvt, wot);
    gemm_bt<0><<<dim3(24, 32), 256, 0, stream>>>(xb, wqkvt, qkv, 4096, 3072, 2048);
    rv_kernel<<<4224, 256, 0, stream>>>(qkv, fc, fs, qb, kb, vtb);
    attn_kernel<<<dim3(16, 32), 512, 0, stream>>>(qb, kb, vtb, attno);
    gemm_bt<1><<<dim3(16, 32), 256, 0, stream>>>(attno, wot, d_out, 4096, 2048, 2048);
}